// Round 10
// baseline (232.918 us; speedup 1.0000x reference)
//
#include <hip/hip_runtime.h>

typedef _Float16 half4 __attribute__((ext_vector_type(4)));
typedef _Float16 half8 __attribute__((ext_vector_type(8)));
typedef __fp16   cvt2  __attribute__((ext_vector_type(2)));
typedef float    f32x4 __attribute__((ext_vector_type(4)));
typedef unsigned int u32x2 __attribute__((ext_vector_type(2)));
typedef unsigned int u32x4 __attribute__((ext_vector_type(4)));

__device__ __forceinline__ unsigned int pkrtz(float a, float b) {
    return __builtin_bit_cast(unsigned int, __builtin_amdgcn_cvt_pkrtz(a, b));
}
__device__ __forceinline__ half4 pack4(float a, float b, float c, float d) {
    u32x2 t; t[0] = pkrtz(a, b); t[1] = pkrtz(c, d);
    return __builtin_bit_cast(half4, t);
}

#define ROWF 256   // floats per token row (H*d = 4*64)
#define HDIM 64
#define KST 72     // K LDS stride in halves (144 B; b128-aligned rows)
#define VST 68     // V LDS stride in halves (136 B; b64 ops at 4-touch bank floor)

// intra-tile token offset: j = tt*64 + th*8 + tw  ->  2304*tt + 48*th + tw
__device__ __forceinline__ int intra_off(int j) {
    return 2304 * (j >> 6) + 48 * ((j >> 3) & 7) + (j & 7);
}

__global__ __launch_bounds__(256) void sta_kernel(
    const float* __restrict__ qg, const float* __restrict__ kg,
    const float* __restrict__ vg, float* __restrict__ out)
{
    __shared__ _Float16 Klds[64 * KST];   // [key][d]
    __shared__ _Float16 Vlds[64 * VST];   // transposed: [d][key]

    const int tid  = threadIdx.x;
    const int wave = tid >> 6;
    const int lane = tid & 63;
    const int g    = lane >> 4;   // 0..3
    const int c    = lane & 15;   // 0..15

    // heavy-first dispatch: hidx 0 -> head 1 (W=4), then heads 0,2,3
    const int bid  = blockIdx.x;
    const int hidx = bid / 432;
    const int rest = bid - hidx * 432;
    const int tile = rest >> 1;         // 0..215
    const int rb   = rest & 1;          // query half
    const int head = (hidx == 0) ? 1 : (hidx == 1 ? 0 : hidx);

    const int nt = tile / 36;
    const int nh = (tile / 6) % 6;
    const int nw = tile % 6;
    const int tbase = 13824 * nt + 384 * nh + 8 * nw;

    // --- window-start base + packed per-window-tile kb deltas (16b each) ---
    int W, kb0; unsigned long long dpk;
    const int t0 = nt < 4 ? nt : 4;
    const int h0 = nh < 4 ? nh : 4;
    const int w0 = nw < 4 ? nw : 4;
    if (head == 0) {        // (2,1,1)
        W = 2; kb0 = 13824 * t0 + 384 * nh + 8 * nw; dpk = (13824ULL << 16);
    } else if (head == 1) { // (1,2,2)
        W = 4; kb0 = 13824 * nt + 384 * h0 + 8 * w0;
        dpk = (8ULL << 16) | (384ULL << 32) | (392ULL << 48);
    } else if (head == 2) { // (1,1,2)
        W = 2; kb0 = 13824 * nt + 384 * nh + 8 * w0; dpk = (8ULL << 16);
    } else {                // (1,1,1)
        W = 1; kb0 = tbase; dpk = 0ULL;
    }
    const int NC = W * 6;

    // --- Q fragments: lane holds Q[q=mt*16+c][d-slice], scale folded (exp2 domain)
    const float qscale = 0.125f * 1.44269504f;
    half8 qf[3][2];
    #pragma unroll
    for (int mt = 0; mt < 3; ++mt) {
        const int j = rb * 192 + wave * 48 + mt * 16 + c;
        const float* qp = qg + (size_t)(tbase + intra_off(j)) * ROWF + head * HDIM;
        #pragma unroll
        for (int kc = 0; kc < 2; ++kc) {
            f32x4 a = *(const f32x4*)(qp + kc * 32 + g * 8);
            f32x4 b = *(const f32x4*)(qp + kc * 32 + g * 8 + 4);
            u32x4 t;
            t[0] = pkrtz(a[0] * qscale, a[1] * qscale);
            t[1] = pkrtz(a[2] * qscale, a[3] * qscale);
            t[2] = pkrtz(b[0] * qscale, b[1] * qscale);
            t[3] = pkrtz(b[2] * qscale, b[3] * qscale);
            qf[mt][kc] = __builtin_bit_cast(half8, t);
        }
    }

    f32x4 oacc[3][4];
    float m_r[3], l_r[3];     // anchor (exp2-domain) + PER-LANE partial row-sum
    bool  anch[3];            // wave-uniform: true once a vote has failed
    #pragma unroll
    for (int mt = 0; mt < 3; ++mt) {
        #pragma unroll
        for (int dt = 0; dt < 4; ++dt) oacc[mt][dt] = (f32x4){0.f, 0.f, 0.f, 0.f};
        m_r[mt] = 0.f; l_r[mt] = 0.f; anch[mt] = false;
    }

    const int r4  = tid >> 4;   // key group of 4 (0..15)
    const int sc4 = tid & 15;   // d group of 4 (0..15)

    int toff0, toff1, toff2, toff3;
    {
        const int r0 = r4 * 4;
        toff0 = 48 * ((r0 + 0) >> 3) + ((r0 + 0) & 7);
        toff1 = 48 * ((r0 + 1) >> 3) + ((r0 + 1) & 7);
        toff2 = 48 * ((r0 + 2) >> 3) + ((r0 + 2) & 7);
        toff3 = 48 * ((r0 + 3) >> 3) + ((r0 + 3) & 7);
    }
    const size_t lin = (size_t)head * HDIM + sc4 * 4;

    f32x4 kr0, kr1, kr2, kr3, vr0, vr1, vr2, vr3;

#define ISSUE_N(N) do {                                                  \
        const int wi_ = (N) / 6;                                         \
        const int kb_ = kb0 + (int)((dpk >> (wi_ * 16)) & 0xFFFFULL)     \
                            + 2304 * ((N) - wi_ * 6);                    \
        const size_t a0 = (size_t)(kb_ + toff0) * ROWF + lin;            \
        const size_t a1 = (size_t)(kb_ + toff1) * ROWF + lin;            \
        const size_t a2 = (size_t)(kb_ + toff2) * ROWF + lin;            \
        const size_t a3 = (size_t)(kb_ + toff3) * ROWF + lin;            \
        kr0 = *(const f32x4*)(kg + a0); vr0 = *(const f32x4*)(vg + a0);  \
        kr1 = *(const f32x4*)(kg + a1); vr1 = *(const f32x4*)(vg + a1);  \
        kr2 = *(const f32x4*)(kg + a2); vr2 = *(const f32x4*)(vg + a2);  \
        kr3 = *(const f32x4*)(kg + a3); vr3 = *(const f32x4*)(vg + a3);  \
    } while (0)

#define COMMIT() do {                                                        \
        *(half4*)&Klds[(r4 * 4 + 0) * KST + sc4 * 4] =                       \
            pack4(kr0[0], kr0[1], kr0[2], kr0[3]);                           \
        *(half4*)&Klds[(r4 * 4 + 1) * KST + sc4 * 4] =                       \
            pack4(kr1[0], kr1[1], kr1[2], kr1[3]);                           \
        *(half4*)&Klds[(r4 * 4 + 2) * KST + sc4 * 4] =                       \
            pack4(kr2[0], kr2[1], kr2[2], kr2[3]);                           \
        *(half4*)&Klds[(r4 * 4 + 3) * KST + sc4 * 4] =                       \
            pack4(kr3[0], kr3[1], kr3[2], kr3[3]);                           \
        _Pragma("unroll")                                                    \
        for (int e = 0; e < 4; ++e) {                                        \
            *(half4*)&Vlds[(sc4 * 4 + e) * VST + r4 * 4] =                   \
                pack4(vr0[e], vr1[e], vr2[e], vr3[e]);                       \
        }                                                                    \
    } while (0)

    ISSUE_N(0);

    for (int ci = 0; ci < NC; ++ci) {
        COMMIT();
        __syncthreads();
        if (ci + 1 < NC) ISSUE_N(ci + 1);

        #pragma unroll
        for (int mt = 0; mt < 3; ++mt) {
            // --- S^T = K * Q^T : lane (g,c) holds S[q=c][key = jt*16 + g*4 + r] ---
            f32x4 sacc[4];
            #pragma unroll
            for (int jt = 0; jt < 4; ++jt) sacc[jt] = (f32x4){0.f, 0.f, 0.f, 0.f};
            #pragma unroll
            for (int kc = 0; kc < 2; ++kc) {
                const half8 qfr = qf[mt][kc];
                #pragma unroll
                for (int jt = 0; jt < 4; ++jt) {
                    const half8 kf = *(const half8*)&Klds[(jt * 16 + c) * KST + kc * 32 + g * 8];
                    sacc[jt] = __builtin_amdgcn_mfma_f32_16x16x32_f16(kf, qfr, sacc[jt], 0, 0, 0);
                }
            }
            // --- per-lane max + wave vote; common path has NO cross-lane, NO subtract ---
            float mj[4];
            #pragma unroll
            for (int jt = 0; jt < 4; ++jt)
                mj[jt] = fmaxf(fmaxf(sacc[jt][0], sacc[jt][1]),
                               fmaxf(sacc[jt][2], sacc[jt][3]));
            const float mm = fmaxf(fmaxf(mj[0], mj[1]), fmaxf(mj[2], mj[3]));

            if (__builtin_expect(!__all(mm <= m_r[mt] + 12.f), 0)) {
                // slow path: true row-max reduce, rescale running state, set anchor
                float mrow = mm;
                mrow = fmaxf(mrow, __shfl_xor(mrow, 16, 64));
                mrow = fmaxf(mrow, __shfl_xor(mrow, 32, 64));
                const float mn = fmaxf(m_r[mt], mrow);
                const float alpha = exp2f(m_r[mt] - mn);
                m_r[mt] = mn;
                anch[mt] = true;               // wave-uniform (vote is uniform)
                l_r[mt] *= alpha;
                float ar[4];
                #pragma unroll
                for (int r = 0; r < 4; ++r) ar[r] = __shfl(alpha, g * 4 + r, 16);
                #pragma unroll
                for (int dt = 0; dt < 4; ++dt)
                    #pragma unroll
                    for (int r = 0; r < 4; ++r)
                        oacc[mt][dt][r] *= ar[r];
            }

            // --- P = exp2(s) (anchor 0) or exp2(s-m) (anchored); packed to f16 ---
            half4 ph[4];
            float rsj[4];
            if (!anch[mt]) {
                #pragma unroll
                for (int jt = 0; jt < 4; ++jt) {
                    const float p0 = exp2f(sacc[jt][0]);
                    const float p1 = exp2f(sacc[jt][1]);
                    const float p2 = exp2f(sacc[jt][2]);
                    const float p3 = exp2f(sacc[jt][3]);
                    rsj[jt] = (p0 + p1) + (p2 + p3);
                    ph[jt] = pack4(p0, p1, p2, p3);
                }
            } else {
                #pragma unroll
                for (int jt = 0; jt < 4; ++jt) {
                    const float p0 = exp2f(sacc[jt][0] - m_r[mt]);
                    const float p1 = exp2f(sacc[jt][1] - m_r[mt]);
                    const float p2 = exp2f(sacc[jt][2] - m_r[mt]);
                    const float p3 = exp2f(sacc[jt][3] - m_r[mt]);
                    rsj[jt] = (p0 + p1) + (p2 + p3);
                    ph[jt] = pack4(p0, p1, p2, p3);
                }
            }
            l_r[mt] += (rsj[0] + rsj[1]) + (rsj[2] + rsj[3]);

            // --- O += P V via 16x16x16: A = P from regs, B = V^T from LDS ---
            #pragma unroll
            for (int jt = 0; jt < 4; ++jt) {
                #pragma unroll
                for (int dt = 0; dt < 4; ++dt) {
                    const half4 vb = *(const half4*)&Vlds[(dt * 16 + c) * VST + jt * 16 + g * 4];
                    oacc[mt][dt] = __builtin_amdgcn_mfma_f32_16x16x16f16(ph[jt], vb, oacc[mt][dt], 0, 0, 0);
                }
            }
        }
        __syncthreads();
    }
#undef ISSUE_N
#undef COMMIT

    // --- epilogue: reduce per-lane l partials once, normalize, scatter via untile ---
    #pragma unroll
    for (int mt = 0; mt < 3; ++mt) {
        float lf = l_r[mt];
        lf += __shfl_xor(lf, 16, 64);
        lf += __shfl_xor(lf, 32, 64);   // full row sum for q=c (uniform across g)
        float lq[4];
        #pragma unroll
        for (int r = 0; r < 4; ++r) lq[r] = __shfl(lf, g * 4 + r, 16);
        #pragma unroll
        for (int r = 0; r < 4; ++r) {
            const int j = rb * 192 + wave * 48 + mt * 16 + g * 4 + r;
            float* op = out + (size_t)(tbase + intra_off(j)) * ROWF + head * HDIM;
            const float linv = 1.0f / lq[r];
            #pragma unroll
            for (int dt = 0; dt < 4; ++dt)
                op[dt * 16 + c] = oacc[mt][dt][r] * linv;
        }
    }
}

extern "C" void kernel_launch(void* const* d_in, const int* in_sizes, int n_in,
                              void* d_out, int out_size, void* d_ws, size_t ws_size,
                              hipStream_t stream) {
    const float* q = (const float*)d_in[0];
    const float* k = (const float*)d_in[1];
    const float* v = (const float*)d_in[2];
    float* o = (float*)d_out;
    dim3 grid(216 * 4 * 2);   // head-major: heavy head first
    dim3 block(256);
    hipLaunchKernelGGL(sta_kernel, grid, block, 0, stream, q, k, v, o);
}

// Round 11
// 186.634 us; speedup vs baseline: 1.2480x; 1.2480x over previous
//
#include <hip/hip_runtime.h>

typedef _Float16 half4 __attribute__((ext_vector_type(4)));
typedef _Float16 half8 __attribute__((ext_vector_type(8)));
typedef __fp16   cvt2  __attribute__((ext_vector_type(2)));
typedef float    f32x4 __attribute__((ext_vector_type(4)));
typedef unsigned int u32x2 __attribute__((ext_vector_type(2)));
typedef unsigned int u32x4 __attribute__((ext_vector_type(4)));

__device__ __forceinline__ unsigned int pkrtz(float a, float b) {
    return __builtin_bit_cast(unsigned int, __builtin_amdgcn_cvt_pkrtz(a, b));
}
__device__ __forceinline__ half4 pack4(float a, float b, float c, float d) {
    u32x2 t; t[0] = pkrtz(a, b); t[1] = pkrtz(c, d);
    return __builtin_bit_cast(half4, t);
}

#define ROWF 256   // floats per token row (H*d = 4*64)
#define HDIM 64
#define KST 72     // K LDS stride in halves (144 B; b128-aligned rows)
#define VST 68     // V LDS stride in halves (136 B; b64 ops at 4-touch bank floor)

// intra-tile token offset: j = tt*64 + th*8 + tw  ->  2304*tt + 48*th + tw
__device__ __forceinline__ int intra_off(int j) {
    return 2304 * (j >> 6) + 48 * ((j >> 3) & 7) + (j & 7);
}

__global__ __launch_bounds__(256) void sta_kernel(
    const float* __restrict__ qg, const float* __restrict__ kg,
    const float* __restrict__ vg, float* __restrict__ out)
{
    __shared__ _Float16 Klds[64 * KST];   // [key][d]
    __shared__ _Float16 Vlds[64 * VST];   // transposed: [d][key]

    const int tid  = threadIdx.x;
    const int wave = tid >> 6;
    const int lane = tid & 63;
    const int g    = lane >> 4;   // 0..3
    const int c    = lane & 15;   // 0..15

    // heavy-first dispatch: hidx 0 -> head 1 (W=4), then heads 0,2,3
    const int bid  = blockIdx.x;
    const int hidx = bid / 432;
    const int rest = bid - hidx * 432;
    const int tile = rest >> 1;         // 0..215
    const int rb   = rest & 1;          // query half
    const int head = (hidx == 0) ? 1 : (hidx == 1 ? 0 : hidx);

    const int nt = tile / 36;
    const int nh = (tile / 6) % 6;
    const int nw = tile % 6;
    const int tbase = 13824 * nt + 384 * nh + 8 * nw;

    // --- window-start base + packed per-window-tile kb deltas (16b each) ---
    int W, kb0; unsigned long long dpk;
    const int t0 = nt < 4 ? nt : 4;
    const int h0 = nh < 4 ? nh : 4;
    const int w0 = nw < 4 ? nw : 4;
    if (head == 0) {        // (2,1,1)
        W = 2; kb0 = 13824 * t0 + 384 * nh + 8 * nw; dpk = (13824ULL << 16);
    } else if (head == 1) { // (1,2,2)
        W = 4; kb0 = 13824 * nt + 384 * h0 + 8 * w0;
        dpk = (8ULL << 16) | (384ULL << 32) | (392ULL << 48);
    } else if (head == 2) { // (1,1,2)
        W = 2; kb0 = 13824 * nt + 384 * nh + 8 * w0; dpk = (8ULL << 16);
    } else {                // (1,1,1)
        W = 1; kb0 = tbase; dpk = 0ULL;
    }
    const int NC = W * 6;

    // --- Q fragments: lane holds Q[q=mt*16+c][d-slice], scale folded (exp2 domain)
    const float qscale = 0.125f * 1.44269504f;
    half8 qf[3][2];
    #pragma unroll
    for (int mt = 0; mt < 3; ++mt) {
        const int j = rb * 192 + wave * 48 + mt * 16 + c;
        const float* qp = qg + (size_t)(tbase + intra_off(j)) * ROWF + head * HDIM;
        #pragma unroll
        for (int kc = 0; kc < 2; ++kc) {
            f32x4 a = *(const f32x4*)(qp + kc * 32 + g * 8);
            f32x4 b = *(const f32x4*)(qp + kc * 32 + g * 8 + 4);
            u32x4 t;
            t[0] = pkrtz(a[0] * qscale, a[1] * qscale);
            t[1] = pkrtz(a[2] * qscale, a[3] * qscale);
            t[2] = pkrtz(b[0] * qscale, b[1] * qscale);
            t[3] = pkrtz(b[2] * qscale, b[3] * qscale);
            qf[mt][kc] = __builtin_bit_cast(half8, t);
        }
    }

    f32x4 oacc[3][4];
    float m_r[3], l_r[3];   // m: per-row anchor (exp2 domain); l: PER-LANE partial sum
    #pragma unroll
    for (int mt = 0; mt < 3; ++mt) {
        #pragma unroll
        for (int dt = 0; dt < 4; ++dt) oacc[mt][dt] = (f32x4){0.f, 0.f, 0.f, 0.f};
        m_r[mt] = 8.0f;     // anchor; sacc init -m makes MFMA emit S-m directly
        l_r[mt] = 0.f;
    }

    const int r4  = tid >> 4;   // key group of 4 (0..15)
    const int sc4 = tid & 15;   // d group of 4 (0..15)

    int toff0, toff1, toff2, toff3;
    {
        const int r0 = r4 * 4;
        toff0 = 48 * ((r0 + 0) >> 3) + ((r0 + 0) & 7);
        toff1 = 48 * ((r0 + 1) >> 3) + ((r0 + 1) & 7);
        toff2 = 48 * ((r0 + 2) >> 3) + ((r0 + 2) & 7);
        toff3 = 48 * ((r0 + 3) >> 3) + ((r0 + 3) & 7);
    }
    const size_t lin = (size_t)head * HDIM + sc4 * 4;

    f32x4 kr0, kr1, kr2, kr3, vr0, vr1, vr2, vr3;

#define ISSUE_N(N) do {                                                  \
        const int wi_ = (N) / 6;                                         \
        const int kb_ = kb0 + (int)((dpk >> (wi_ * 16)) & 0xFFFFULL)     \
                            + 2304 * ((N) - wi_ * 6);                    \
        const size_t a0 = (size_t)(kb_ + toff0) * ROWF + lin;            \
        const size_t a1 = (size_t)(kb_ + toff1) * ROWF + lin;            \
        const size_t a2 = (size_t)(kb_ + toff2) * ROWF + lin;            \
        const size_t a3 = (size_t)(kb_ + toff3) * ROWF + lin;            \
        kr0 = *(const f32x4*)(kg + a0); vr0 = *(const f32x4*)(vg + a0);  \
        kr1 = *(const f32x4*)(kg + a1); vr1 = *(const f32x4*)(vg + a1);  \
        kr2 = *(const f32x4*)(kg + a2); vr2 = *(const f32x4*)(vg + a2);  \
        kr3 = *(const f32x4*)(kg + a3); vr3 = *(const f32x4*)(vg + a3);  \
    } while (0)

#define COMMIT() do {                                                        \
        *(half4*)&Klds[(r4 * 4 + 0) * KST + sc4 * 4] =                       \
            pack4(kr0[0], kr0[1], kr0[2], kr0[3]);                           \
        *(half4*)&Klds[(r4 * 4 + 1) * KST + sc4 * 4] =                       \
            pack4(kr1[0], kr1[1], kr1[2], kr1[3]);                           \
        *(half4*)&Klds[(r4 * 4 + 2) * KST + sc4 * 4] =                       \
            pack4(kr2[0], kr2[1], kr2[2], kr2[3]);                           \
        *(half4*)&Klds[(r4 * 4 + 3) * KST + sc4 * 4] =                       \
            pack4(kr3[0], kr3[1], kr3[2], kr3[3]);                           \
        _Pragma("unroll")                                                    \
        for (int e = 0; e < 4; ++e) {                                        \
            *(half4*)&Vlds[(sc4 * 4 + e) * VST + r4 * 4] =                   \
                pack4(vr0[e], vr1[e], vr2[e], vr3[e]);                       \
        }                                                                    \
    } while (0)

    ISSUE_N(0);

    for (int ci = 0; ci < NC; ++ci) {
        COMMIT();
        __syncthreads();
        if (ci + 1 < NC) ISSUE_N(ci + 1);

        #pragma unroll
        for (int mt = 0; mt < 3; ++mt) {
            // --- S^T - m = K*Q^T + C(-m) : C-input carries the softmax anchor ---
            const float nm = -m_r[mt];
            f32x4 sacc[4];
            #pragma unroll
            for (int jt = 0; jt < 4; ++jt) sacc[jt] = (f32x4){nm, nm, nm, nm};
            #pragma unroll
            for (int kc = 0; kc < 2; ++kc) {
                const half8 qfr = qf[mt][kc];
                #pragma unroll
                for (int jt = 0; jt < 4; ++jt) {
                    const half8 kf = *(const half8*)&Klds[(jt * 16 + c) * KST + kc * 32 + g * 8];
                    sacc[jt] = __builtin_amdgcn_mfma_f32_16x16x32_f16(kf, qfr, sacc[jt], 0, 0, 0);
                }
            }
            // --- per-lane max + wave vote; common path: NO cross-lane, NO subtract ---
            float mj[4];
            #pragma unroll
            for (int jt = 0; jt < 4; ++jt)
                mj[jt] = fmaxf(fmaxf(sacc[jt][0], sacc[jt][1]),
                               fmaxf(sacc[jt][2], sacc[jt][3]));
            const float mm = fmaxf(fmaxf(mj[0], mj[1]), fmaxf(mj[2], mj[3]));

            if (__builtin_expect(!__all(mm <= 12.f), 0)) {
                // slow path (sacc-domain): per-row max over g, shift anchor by delta
                float mrow = mm;
                mrow = fmaxf(mrow, __shfl_xor(mrow, 16, 64));
                mrow = fmaxf(mrow, __shfl_xor(mrow, 32, 64));
                const float delta = fmaxf(mrow, 0.f);    // row q=c anchor shift
                const float alpha = exp2f(-delta);
                m_r[mt] += delta;
                l_r[mt] *= alpha;
                #pragma unroll
                for (int jt = 0; jt < 4; ++jt)
                    #pragma unroll
                    for (int e = 0; e < 4; ++e)
                        sacc[jt][e] -= delta;
                float ar[4];
                #pragma unroll
                for (int r = 0; r < 4; ++r) ar[r] = __shfl(alpha, g * 4 + r, 16);
                #pragma unroll
                for (int dt = 0; dt < 4; ++dt)
                    #pragma unroll
                    for (int r = 0; r < 4; ++r)
                        oacc[mt][dt][r] *= ar[r];
            }

            // --- P = exp2(sacc) in registers, packed f16; per-lane partial l ---
            half4 ph[4];
            float rsj[4];
            #pragma unroll
            for (int jt = 0; jt < 4; ++jt) {
                const float p0 = exp2f(sacc[jt][0]);
                const float p1 = exp2f(sacc[jt][1]);
                const float p2 = exp2f(sacc[jt][2]);
                const float p3 = exp2f(sacc[jt][3]);
                rsj[jt] = (p0 + p1) + (p2 + p3);
                ph[jt] = pack4(p0, p1, p2, p3);
            }
            l_r[mt] += (rsj[0] + rsj[1]) + (rsj[2] + rsj[3]);

            // --- O += P V via 16x16x16: A = P from regs, B = V^T from LDS ---
            #pragma unroll
            for (int jt = 0; jt < 4; ++jt) {
                #pragma unroll
                for (int dt = 0; dt < 4; ++dt) {
                    const half4 vb = *(const half4*)&Vlds[(dt * 16 + c) * VST + jt * 16 + g * 4];
                    oacc[mt][dt] = __builtin_amdgcn_mfma_f32_16x16x16f16(ph[jt], vb, oacc[mt][dt], 0, 0, 0);
                }
            }
        }
        __syncthreads();
    }
#undef ISSUE_N
#undef COMMIT

    // --- epilogue: reduce per-lane l partials once, normalize, scatter via untile ---
    #pragma unroll
    for (int mt = 0; mt < 3; ++mt) {
        float lf = l_r[mt];
        lf += __shfl_xor(lf, 16, 64);
        lf += __shfl_xor(lf, 32, 64);   // full row sum for q=c (uniform across g)
        float lq[4];
        #pragma unroll
        for (int r = 0; r < 4; ++r) lq[r] = __shfl(lf, g * 4 + r, 16);
        #pragma unroll
        for (int r = 0; r < 4; ++r) {
            const int j = rb * 192 + wave * 48 + mt * 16 + g * 4 + r;
            float* op = out + (size_t)(tbase + intra_off(j)) * ROWF + head * HDIM;
            const float linv = 1.0f / lq[r];
            #pragma unroll
            for (int dt = 0; dt < 4; ++dt)
                op[dt * 16 + c] = oacc[mt][dt][r] * linv;
        }
    }
}

extern "C" void kernel_launch(void* const* d_in, const int* in_sizes, int n_in,
                              void* d_out, int out_size, void* d_ws, size_t ws_size,
                              hipStream_t stream) {
    const float* q = (const float*)d_in[0];
    const float* k = (const float*)d_in[1];
    const float* v = (const float*)d_in[2];
    float* o = (float*)d_out;
    dim3 grid(216 * 4 * 2);   // head-major: heavy head first
    dim3 block(256);
    hipLaunchKernelGGL(sta_kernel, grid, block, 0, stream, q, k, v, o);
}

// Round 12
// 180.183 us; speedup vs baseline: 1.2927x; 1.0358x over previous
//
#include <hip/hip_runtime.h>

typedef _Float16 half4 __attribute__((ext_vector_type(4)));
typedef _Float16 half8 __attribute__((ext_vector_type(8)));
typedef __fp16   cvt2  __attribute__((ext_vector_type(2)));
typedef float    f32x4 __attribute__((ext_vector_type(4)));
typedef unsigned int u32x2 __attribute__((ext_vector_type(2)));
typedef unsigned int u32x4 __attribute__((ext_vector_type(4)));

__device__ __forceinline__ unsigned int pkrtz(float a, float b) {
    return __builtin_bit_cast(unsigned int, __builtin_amdgcn_cvt_pkrtz(a, b));
}
__device__ __forceinline__ half4 pack4(float a, float b, float c, float d) {
    u32x2 t; t[0] = pkrtz(a, b); t[1] = pkrtz(c, d);
    return __builtin_bit_cast(half4, t);
}

#define ROWF 256   // floats per token row (H*d = 4*64)
#define HDIM 64
#define KST 72     // K LDS stride in halves (144 B; b128-aligned rows)
#define VST 132    // V LDS stride in halves (264 B; same bank pattern as old 68)

// intra-tile token offset: j = tt*64 + th*8 + tw  ->  2304*tt + 48*th + tw
__device__ __forceinline__ int intra_off(int j) {
    return 2304 * (j >> 6) + 48 * ((j >> 3) & 7) + (j & 7);
}

__global__ __launch_bounds__(512) void sta_kernel(
    const float* __restrict__ qg, const float* __restrict__ kg,
    const float* __restrict__ vg, float* __restrict__ out)
{
    __shared__ _Float16 Klds[128 * KST];  // [key 0..127][d]
    __shared__ _Float16 Vlds[64 * VST];   // transposed: [d][key 0..127]

    const int tid  = threadIdx.x;
    const int wave = tid >> 6;    // 0..7 : q rows wave*48..+47
    const int lane = tid & 63;
    const int g    = lane >> 4;   // 0..3
    const int c    = lane & 15;   // 0..15

    // heavy-first dispatch: hidx 0 -> head 1 (W=4), then heads 0,2,3
    const int bid  = blockIdx.x;
    const int hidx = bid / 216;
    const int tile = bid - hidx * 216;
    const int head = (hidx == 0) ? 1 : (hidx == 1 ? 0 : hidx);

    const int nt = tile / 36;
    const int nh = (tile / 6) % 6;
    const int nw = tile % 6;
    const int tbase = 13824 * nt + 384 * nh + 8 * nw;

    // --- window-start base + packed per-window-tile kb deltas (16b each) ---
    int W, kb0; unsigned long long dpk;
    const int t0 = nt < 4 ? nt : 4;
    const int h0 = nh < 4 ? nh : 4;
    const int w0 = nw < 4 ? nw : 4;
    if (head == 0) {        // (2,1,1)
        W = 2; kb0 = 13824 * t0 + 384 * nh + 8 * nw; dpk = (13824ULL << 16);
    } else if (head == 1) { // (1,2,2)
        W = 4; kb0 = 13824 * nt + 384 * h0 + 8 * w0;
        dpk = (8ULL << 16) | (384ULL << 32) | (392ULL << 48);
    } else if (head == 2) { // (1,1,2)
        W = 2; kb0 = 13824 * nt + 384 * nh + 8 * w0; dpk = (8ULL << 16);
    } else {                // (1,1,1)
        W = 1; kb0 = tbase; dpk = 0ULL;
    }
    const int NC = W * 3;   // 128-key chunks

    // --- Q fragments: lane holds Q[q = wave*48 + mt*16 + c][d-slice] ---
    const float qscale = 0.125f * 1.44269504f;   // 1/sqrt(64) * log2(e)
    half8 qf[3][2];
    #pragma unroll
    for (int mt = 0; mt < 3; ++mt) {
        const int j = wave * 48 + mt * 16 + c;
        const float* qp = qg + (size_t)(tbase + intra_off(j)) * ROWF + head * HDIM;
        #pragma unroll
        for (int kc = 0; kc < 2; ++kc) {
            f32x4 a = *(const f32x4*)(qp + kc * 32 + g * 8);
            f32x4 b = *(const f32x4*)(qp + kc * 32 + g * 8 + 4);
            u32x4 t;
            t[0] = pkrtz(a[0] * qscale, a[1] * qscale);
            t[1] = pkrtz(a[2] * qscale, a[3] * qscale);
            t[2] = pkrtz(b[0] * qscale, b[1] * qscale);
            t[3] = pkrtz(b[2] * qscale, b[3] * qscale);
            qf[mt][kc] = __builtin_bit_cast(half8, t);
        }
    }

    f32x4 oacc[3][4];
    float m_r[3], l_r[3];   // m: per-row anchor (exp2 domain); l: PER-LANE partial sum
    #pragma unroll
    for (int mt = 0; mt < 3; ++mt) {
        #pragma unroll
        for (int dt = 0; dt < 4; ++dt) oacc[mt][dt] = (f32x4){0.f, 0.f, 0.f, 0.f};
        m_r[mt] = 8.0f;     // anchor folded into MFMA C-init
        l_r[mt] = 0.f;
    }

    const int r4  = tid >> 4;   // key group of 4 (0..31) within 128-key chunk
    const int sc4 = tid & 15;   // d group of 4 (0..15)

    int toff0, toff1, toff2, toff3;
    {
        const int r0 = r4 * 4;
        toff0 = intra_off(r0 + 0);
        toff1 = intra_off(r0 + 1);
        toff2 = intra_off(r0 + 2);
        toff3 = intra_off(r0 + 3);
    }
    const size_t lin = (size_t)head * HDIM + sc4 * 4;

    f32x4 kr0, kr1, kr2, kr3, vr0, vr1, vr2, vr3;

#define ISSUE_N(N) do {                                                  \
        const int wi_ = (N) / 3;                                         \
        const int kb_ = kb0 + (int)((dpk >> (wi_ * 16)) & 0xFFFFULL)     \
                            + 4608 * ((N) - wi_ * 3);                    \
        const size_t a0 = (size_t)(kb_ + toff0) * ROWF + lin;            \
        const size_t a1 = (size_t)(kb_ + toff1) * ROWF + lin;            \
        const size_t a2 = (size_t)(kb_ + toff2) * ROWF + lin;            \
        const size_t a3 = (size_t)(kb_ + toff3) * ROWF + lin;            \
        kr0 = *(const f32x4*)(kg + a0); vr0 = *(const f32x4*)(vg + a0);  \
        kr1 = *(const f32x4*)(kg + a1); vr1 = *(const f32x4*)(vg + a1);  \
        kr2 = *(const f32x4*)(kg + a2); vr2 = *(const f32x4*)(vg + a2);  \
        kr3 = *(const f32x4*)(kg + a3); vr3 = *(const f32x4*)(vg + a3);  \
    } while (0)

#define COMMIT() do {                                                        \
        *(half4*)&Klds[(r4 * 4 + 0) * KST + sc4 * 4] =                       \
            pack4(kr0[0], kr0[1], kr0[2], kr0[3]);                           \
        *(half4*)&Klds[(r4 * 4 + 1) * KST + sc4 * 4] =                       \
            pack4(kr1[0], kr1[1], kr1[2], kr1[3]);                           \
        *(half4*)&Klds[(r4 * 4 + 2) * KST + sc4 * 4] =                       \
            pack4(kr2[0], kr2[1], kr2[2], kr2[3]);                           \
        *(half4*)&Klds[(r4 * 4 + 3) * KST + sc4 * 4] =                       \
            pack4(kr3[0], kr3[1], kr3[2], kr3[3]);                           \
        _Pragma("unroll")                                                    \
        for (int e = 0; e < 4; ++e) {                                        \
            *(half4*)&Vlds[(sc4 * 4 + e) * VST + r4 * 4] =                   \
                pack4(vr0[e], vr1[e], vr2[e], vr3[e]);                       \
        }                                                                    \
    } while (0)

    ISSUE_N(0);

    for (int ci = 0; ci < NC; ++ci) {
        COMMIT();
        __syncthreads();
        if (ci + 1 < NC) ISSUE_N(ci + 1);

        #pragma unroll
        for (int sub = 0; sub < 2; ++sub) {   // two 64-key sub-blocks per staged chunk
            #pragma unroll
            for (int mt = 0; mt < 3; ++mt) {
                // --- S^T - m = K*Q^T + C(-m) ---
                const float nm = -m_r[mt];
                f32x4 sacc[4];
                #pragma unroll
                for (int jt = 0; jt < 4; ++jt) sacc[jt] = (f32x4){nm, nm, nm, nm};
                #pragma unroll
                for (int kc = 0; kc < 2; ++kc) {
                    const half8 qfr = qf[mt][kc];
                    #pragma unroll
                    for (int jt = 0; jt < 4; ++jt) {
                        const half8 kf = *(const half8*)
                            &Klds[(sub * 64 + jt * 16 + c) * KST + kc * 32 + g * 8];
                        sacc[jt] = __builtin_amdgcn_mfma_f32_16x16x32_f16(kf, qfr, sacc[jt], 0, 0, 0);
                    }
                }
                // --- per-lane max (max3-fusable chains) + wave vote ---
                float m0 = fmaxf(fmaxf(fmaxf(sacc[0][0], sacc[0][1]), sacc[0][2]), sacc[0][3]);
                float m1 = fmaxf(fmaxf(fmaxf(sacc[1][0], sacc[1][1]), sacc[1][2]), sacc[1][3]);
                float m2 = fmaxf(fmaxf(fmaxf(sacc[2][0], sacc[2][1]), sacc[2][2]), sacc[2][3]);
                float m3 = fmaxf(fmaxf(fmaxf(sacc[3][0], sacc[3][1]), sacc[3][2]), sacc[3][3]);
                const float mm = fmaxf(fmaxf(fmaxf(m0, m1), m2), m3);

                if (__builtin_expect(!__all(mm <= 12.f), 0)) {
                    // slow path: per-row reduce in sacc domain, shift anchor
                    float mrow = mm;
                    mrow = fmaxf(mrow, __shfl_xor(mrow, 16, 64));
                    mrow = fmaxf(mrow, __shfl_xor(mrow, 32, 64));
                    const float delta = fmaxf(mrow, 0.f);
                    const float alpha = exp2f(-delta);
                    m_r[mt] += delta;
                    l_r[mt] *= alpha;
                    #pragma unroll
                    for (int jt = 0; jt < 4; ++jt)
                        #pragma unroll
                        for (int e = 0; e < 4; ++e)
                            sacc[jt][e] -= delta;
                    float ar[4];
                    #pragma unroll
                    for (int r = 0; r < 4; ++r) ar[r] = __shfl(alpha, g * 4 + r, 16);
                    #pragma unroll
                    for (int dt = 0; dt < 4; ++dt)
                        #pragma unroll
                        for (int r = 0; r < 4; ++r)
                            oacc[mt][dt][r] *= ar[r];
                }

                // --- P = exp2(sacc), packed f16; per-lane partial l ---
                half4 ph[4];
                float rsj[4];
                #pragma unroll
                for (int jt = 0; jt < 4; ++jt) {
                    const float p0 = exp2f(sacc[jt][0]);
                    const float p1 = exp2f(sacc[jt][1]);
                    const float p2 = exp2f(sacc[jt][2]);
                    const float p3 = exp2f(sacc[jt][3]);
                    rsj[jt] = (p0 + p1) + (p2 + p3);
                    ph[jt] = pack4(p0, p1, p2, p3);
                }
                l_r[mt] += (rsj[0] + rsj[1]) + (rsj[2] + rsj[3]);

                // --- O += P V via 16x16x16: A = P from regs, B = V^T from LDS ---
                #pragma unroll
                for (int jt = 0; jt < 4; ++jt) {
                    #pragma unroll
                    for (int dt = 0; dt < 4; ++dt) {
                        const half4 vb = *(const half4*)
                            &Vlds[(dt * 16 + c) * VST + sub * 64 + jt * 16 + g * 4];
                        oacc[mt][dt] = __builtin_amdgcn_mfma_f32_16x16x16f16(ph[jt], vb, oacc[mt][dt], 0, 0, 0);
                    }
                }
            }
        }
        __syncthreads();
    }
#undef ISSUE_N
#undef COMMIT

    // --- epilogue: reduce per-lane l partials once, normalize, scatter via untile ---
    #pragma unroll
    for (int mt = 0; mt < 3; ++mt) {
        float lf = l_r[mt];
        lf += __shfl_xor(lf, 16, 64);
        lf += __shfl_xor(lf, 32, 64);   // full row sum for q=c (uniform across g)
        float lq[4];
        #pragma unroll
        for (int r = 0; r < 4; ++r) lq[r] = __shfl(lf, g * 4 + r, 16);
        #pragma unroll
        for (int r = 0; r < 4; ++r) {
            const int j = wave * 48 + mt * 16 + g * 4 + r;
            float* op = out + (size_t)(tbase + intra_off(j)) * ROWF + head * HDIM;
            const float linv = 1.0f / lq[r];
            #pragma unroll
            for (int dt = 0; dt < 4; ++dt)
                op[dt * 16 + c] = oacc[mt][dt][r] * linv;
        }
    }
}

extern "C" void kernel_launch(void* const* d_in, const int* in_sizes, int n_in,
                              void* d_out, int out_size, void* d_ws, size_t ws_size,
                              hipStream_t stream) {
    const float* q = (const float*)d_in[0];
    const float* k = (const float*)d_in[1];
    const float* v = (const float*)d_in[2];
    float* o = (float*)d_out;
    dim3 grid(216 * 4);     // one block per (tile, head); heavy head first
    dim3 block(512);        // 8 waves x 48 q-rows = 384
    hipLaunchKernelGGL(sta_kernel, grid, block, 0, stream, q, k, v, o);
}

// Round 13
// 167.580 us; speedup vs baseline: 1.3899x; 1.0752x over previous
//
#include <hip/hip_runtime.h>

typedef _Float16 half4 __attribute__((ext_vector_type(4)));
typedef _Float16 half8 __attribute__((ext_vector_type(8)));
typedef __fp16   cvt2  __attribute__((ext_vector_type(2)));
typedef float    f32x4 __attribute__((ext_vector_type(4)));
typedef unsigned int u32x2 __attribute__((ext_vector_type(2)));
typedef unsigned int u32x4 __attribute__((ext_vector_type(4)));

__device__ __forceinline__ unsigned int pkrtz(float a, float b) {
    return __builtin_bit_cast(unsigned int, __builtin_amdgcn_cvt_pkrtz(a, b));
}
__device__ __forceinline__ half4 pack4(float a, float b, float c, float d) {
    u32x2 t; t[0] = pkrtz(a, b); t[1] = pkrtz(c, d);
    return __builtin_bit_cast(half4, t);
}
__device__ __forceinline__ half8 cat8(half4 lo, half4 hi) {
    u32x2 l = __builtin_bit_cast(u32x2, lo), h = __builtin_bit_cast(u32x2, hi);
    u32x4 t; t[0] = l[0]; t[1] = l[1]; t[2] = h[0]; t[3] = h[1];
    return __builtin_bit_cast(half8, t);
}

#define ROWF 256   // floats per token row (H*d = 4*64)
#define HDIM 64
#define KST 72     // K LDS stride in halves (144 B; b128-aligned rows)
#define VST 136    // V LDS stride in halves (272 B = 17x16B; b128-aligned rows)

// intra-tile token offset: j = tt*64 + th*8 + tw  ->  2304*tt + 48*th + tw
__device__ __forceinline__ int intra_off(int j) {
    return 2304 * (j >> 6) + 48 * ((j >> 3) & 7) + (j & 7);
}

// K LDS row permutation: key bits kc:g:b:r -> row bits kc:b:g:r.
// Makes S^T land so each lane holds P[q][32kc+8g+e] = 16x16x32 A-frag.
__device__ __forceinline__ int kperm(int x) {
    return (x & 0x23) | ((x & 0x18) >> 1) | ((x & 4) << 2);
}

__global__ __launch_bounds__(512) void sta_kernel(
    const float* __restrict__ qg, const float* __restrict__ kg,
    const float* __restrict__ vg, float* __restrict__ out)
{
    __shared__ _Float16 Klds[128 * KST];  // [row perm(key)][d]
    __shared__ _Float16 Vlds[64 * VST];   // transposed: [d][key 0..127] natural order

    const int tid  = threadIdx.x;
    const int wave = tid >> 6;    // 0..7 : q rows wave*48..+47
    const int lane = tid & 63;
    const int g    = lane >> 4;   // 0..3
    const int c    = lane & 15;   // 0..15

    // heavy-first dispatch: hidx 0 -> head 1 (W=4), then heads 0,2,3
    const int bid  = blockIdx.x;
    const int hidx = bid / 216;
    const int tile = bid - hidx * 216;
    const int head = (hidx == 0) ? 1 : (hidx == 1 ? 0 : hidx);

    const int nt = tile / 36;
    const int nh = (tile / 6) % 6;
    const int nw = tile % 6;
    const int tbase = 13824 * nt + 384 * nh + 8 * nw;

    // --- window-start base + packed per-window-tile kb deltas (16b each) ---
    int W, kb0; unsigned long long dpk;
    const int t0 = nt < 4 ? nt : 4;
    const int h0 = nh < 4 ? nh : 4;
    const int w0 = nw < 4 ? nw : 4;
    if (head == 0) {        // (2,1,1)
        W = 2; kb0 = 13824 * t0 + 384 * nh + 8 * nw; dpk = (13824ULL << 16);
    } else if (head == 1) { // (1,2,2)
        W = 4; kb0 = 13824 * nt + 384 * h0 + 8 * w0;
        dpk = (8ULL << 16) | (384ULL << 32) | (392ULL << 48);
    } else if (head == 2) { // (1,1,2)
        W = 2; kb0 = 13824 * nt + 384 * nh + 8 * w0; dpk = (8ULL << 16);
    } else {                // (1,1,1)
        W = 1; kb0 = tbase; dpk = 0ULL;
    }
    const int NC = W * 3;   // 128-key chunks

    // --- Q fragments: lane holds Q[q = wave*48 + mt*16 + c][d-slice] ---
    const float qscale = 0.125f * 1.44269504f;   // 1/sqrt(64) * log2(e)
    half8 qf[3][2];
    #pragma unroll
    for (int mt = 0; mt < 3; ++mt) {
        const int j = wave * 48 + mt * 16 + c;
        const float* qp = qg + (size_t)(tbase + intra_off(j)) * ROWF + head * HDIM;
        #pragma unroll
        for (int kc = 0; kc < 2; ++kc) {
            f32x4 a = *(const f32x4*)(qp + kc * 32 + g * 8);
            f32x4 b = *(const f32x4*)(qp + kc * 32 + g * 8 + 4);
            u32x4 t;
            t[0] = pkrtz(a[0] * qscale, a[1] * qscale);
            t[1] = pkrtz(a[2] * qscale, a[3] * qscale);
            t[2] = pkrtz(b[0] * qscale, b[1] * qscale);
            t[3] = pkrtz(b[2] * qscale, b[3] * qscale);
            qf[mt][kc] = __builtin_bit_cast(half8, t);
        }
    }

    // ones B-operand for the l row-sum MFMA (constant, register-only)
    u32x4 onep; onep[0] = onep[1] = onep[2] = onep[3] = 0x3C003C00u;
    const half8 ones8 = __builtin_bit_cast(half8, onep);

    f32x4 oacc[3][4];
    f32x4 lacc[3];          // row-sum accumulator, same row domain as oacc (q=g*4+r)
    float m_r[3];           // per-row anchor (exp2 domain), folded into MFMA C-init
    #pragma unroll
    for (int mt = 0; mt < 3; ++mt) {
        #pragma unroll
        for (int dt = 0; dt < 4; ++dt) oacc[mt][dt] = (f32x4){0.f, 0.f, 0.f, 0.f};
        lacc[mt] = (f32x4){0.f, 0.f, 0.f, 0.f};
        m_r[mt] = 8.0f;
    }

    const int r4  = tid >> 4;   // key group of 4 (0..31) within 128-key chunk
    const int sc4 = tid & 15;   // d group of 4 (0..15)

    int toff0, toff1, toff2, toff3, krow0;
    {
        const int r0 = r4 * 4;
        toff0 = intra_off(r0 + 0);
        toff1 = intra_off(r0 + 1);
        toff2 = intra_off(r0 + 2);
        toff3 = intra_off(r0 + 3);
        krow0 = (r0 & 64) + kperm(r0 & 63);   // permuted LDS row (j adds to r-bits)
    }
    const size_t lin = (size_t)head * HDIM + sc4 * 4;

    f32x4 kr0, kr1, kr2, kr3, vr0, vr1, vr2, vr3;

#define ISSUE_N(N) do {                                                  \
        const int wi_ = (N) / 3;                                         \
        const int kb_ = kb0 + (int)((dpk >> (wi_ * 16)) & 0xFFFFULL)     \
                            + 4608 * ((N) - wi_ * 3);                    \
        const size_t a0 = (size_t)(kb_ + toff0) * ROWF + lin;            \
        const size_t a1 = (size_t)(kb_ + toff1) * ROWF + lin;            \
        const size_t a2 = (size_t)(kb_ + toff2) * ROWF + lin;            \
        const size_t a3 = (size_t)(kb_ + toff3) * ROWF + lin;            \
        kr0 = *(const f32x4*)(kg + a0); vr0 = *(const f32x4*)(vg + a0);  \
        kr1 = *(const f32x4*)(kg + a1); vr1 = *(const f32x4*)(vg + a1);  \
        kr2 = *(const f32x4*)(kg + a2); vr2 = *(const f32x4*)(vg + a2);  \
        kr3 = *(const f32x4*)(kg + a3); vr3 = *(const f32x4*)(vg + a3);  \
    } while (0)

#define COMMIT() do {                                                        \
        *(half4*)&Klds[(krow0 + 0) * KST + sc4 * 4] =                        \
            pack4(kr0[0], kr0[1], kr0[2], kr0[3]);                           \
        *(half4*)&Klds[(krow0 + 1) * KST + sc4 * 4] =                        \
            pack4(kr1[0], kr1[1], kr1[2], kr1[3]);                           \
        *(half4*)&Klds[(krow0 + 2) * KST + sc4 * 4] =                        \
            pack4(kr2[0], kr2[1], kr2[2], kr2[3]);                           \
        *(half4*)&Klds[(krow0 + 3) * KST + sc4 * 4] =                        \
            pack4(kr3[0], kr3[1], kr3[2], kr3[3]);                           \
        _Pragma("unroll")                                                    \
        for (int e = 0; e < 4; ++e) {                                        \
            *(half4*)&Vlds[(sc4 * 4 + e) * VST + r4 * 4] =                   \
                pack4(vr0[e], vr1[e], vr2[e], vr3[e]);                       \
        }                                                                    \
    } while (0)

    ISSUE_N(0);

    for (int ci = 0; ci < NC; ++ci) {
        COMMIT();
        __syncthreads();
        if (ci + 1 < NC) ISSUE_N(ci + 1);

        #pragma unroll
        for (int sub = 0; sub < 2; ++sub) {   // two 64-key sub-blocks per staged chunk
            #pragma unroll
            for (int mt = 0; mt < 3; ++mt) {
                // --- S^T - m = K*Q^T + C(-m) ; K rows sigma-permuted ---
                const float nm = -m_r[mt];
                f32x4 sacc[4];
                #pragma unroll
                for (int jt = 0; jt < 4; ++jt) sacc[jt] = (f32x4){nm, nm, nm, nm};
                #pragma unroll
                for (int kc = 0; kc < 2; ++kc) {
                    const half8 qfr = qf[mt][kc];
                    #pragma unroll
                    for (int jt = 0; jt < 4; ++jt) {
                        const half8 kf = *(const half8*)
                            &Klds[(sub * 64 + jt * 16 + c) * KST + kc * 32 + g * 8];
                        sacc[jt] = __builtin_amdgcn_mfma_f32_16x16x32_f16(kf, qfr, sacc[jt], 0, 0, 0);
                    }
                }
                // --- per-lane max + wave vote (order-independent) ---
                float m0 = fmaxf(fmaxf(fmaxf(sacc[0][0], sacc[0][1]), sacc[0][2]), sacc[0][3]);
                float m1 = fmaxf(fmaxf(fmaxf(sacc[1][0], sacc[1][1]), sacc[1][2]), sacc[1][3]);
                float m2 = fmaxf(fmaxf(fmaxf(sacc[2][0], sacc[2][1]), sacc[2][2]), sacc[2][3]);
                float m3 = fmaxf(fmaxf(fmaxf(sacc[3][0], sacc[3][1]), sacc[3][2]), sacc[3][3]);
                const float mm = fmaxf(fmaxf(fmaxf(m0, m1), m2), m3);

                if (__builtin_expect(!__all(mm <= 12.f), 0)) {
                    // slow path: per-row reduce in sacc domain, shift anchor
                    float mrow = mm;
                    mrow = fmaxf(mrow, __shfl_xor(mrow, 16, 64));
                    mrow = fmaxf(mrow, __shfl_xor(mrow, 32, 64));
                    const float delta = fmaxf(mrow, 0.f);
                    const float alpha = exp2f(-delta);
                    m_r[mt] += delta;
                    #pragma unroll
                    for (int jt = 0; jt < 4; ++jt)
                        #pragma unroll
                        for (int e = 0; e < 4; ++e)
                            sacc[jt][e] -= delta;
                    float ar[4];
                    #pragma unroll
                    for (int r = 0; r < 4; ++r) ar[r] = __shfl(alpha, g * 4 + r, 16);
                    #pragma unroll
                    for (int r = 0; r < 4; ++r) {
                        lacc[mt][r] *= ar[r];
                        #pragma unroll
                        for (int dt = 0; dt < 4; ++dt)
                            oacc[mt][dt][r] *= ar[r];
                    }
                }

                // --- P = exp2(sacc), packed f16 (keys 32kc+8g+e in-lane) ---
                half4 ph[4];
                #pragma unroll
                for (int jt = 0; jt < 4; ++jt) {
                    ph[jt] = pack4(exp2f(sacc[jt][0]), exp2f(sacc[jt][1]),
                                   exp2f(sacc[jt][2]), exp2f(sacc[jt][3]));
                }

                // --- O += P V and l += P*ones via 16x16x32 ---
                #pragma unroll
                for (int kc = 0; kc < 2; ++kc) {
                    const half8 pa = cat8(ph[2 * kc], ph[2 * kc + 1]);
                    lacc[mt] = __builtin_amdgcn_mfma_f32_16x16x32_f16(pa, ones8, lacc[mt], 0, 0, 0);
                    #pragma unroll
                    for (int dt = 0; dt < 4; ++dt) {
                        const half8 vb = *(const half8*)
                            &Vlds[(dt * 16 + c) * VST + sub * 64 + kc * 32 + g * 8];
                        oacc[mt][dt] = __builtin_amdgcn_mfma_f32_16x16x32_f16(pa, vb, oacc[mt][dt], 0, 0, 0);
                    }
                }
            }
        }
        __syncthreads();
    }
#undef ISSUE_N
#undef COMMIT

    // --- epilogue: lacc already in oacc row domain; normalize, scatter via untile ---
    #pragma unroll
    for (int mt = 0; mt < 3; ++mt) {
        #pragma unroll
        for (int r = 0; r < 4; ++r) {
            const int j = wave * 48 + mt * 16 + g * 4 + r;
            float* op = out + (size_t)(tbase + intra_off(j)) * ROWF + head * HDIM;
            const float linv = 1.0f / lacc[mt][r];
            #pragma unroll
            for (int dt = 0; dt < 4; ++dt)
                op[dt * 16 + c] = oacc[mt][dt][r] * linv;
        }
    }
}

extern "C" void kernel_launch(void* const* d_in, const int* in_sizes, int n_in,
                              void* d_out, int out_size, void* d_ws, size_t ws_size,
                              hipStream_t stream) {
    const float* q = (const float*)d_in[0];
    const float* k = (const float*)d_in[1];
    const float* v = (const float*)d_in[2];
    float* o = (float*)d_out;
    dim3 grid(216 * 4);     // one block per (tile, head); heavy head first
    dim3 block(512);        // 8 waves x 48 q-rows = 384
    hipLaunchKernelGGL(sta_kernel, grid, block, 0, stream, q, k, v, o);
}